// Round 3
// baseline (790.239 us; speedup 1.0000x reference)
//
#include <hip/hip_runtime.h>
#include <hip/hip_bf16.h>

#define TOKENS 16384
#define DMODEL 4096
#define NCH 8
#define CH 512
#define BM 64

typedef short s16x8 __attribute__((ext_vector_type(8)));
typedef float f32x4 __attribute__((ext_vector_type(4)));

__device__ __forceinline__ unsigned short f2bf(float f) {
    unsigned u = __float_as_uint(f);
    u += 0x7fffu + ((u >> 16) & 1u);
    return (unsigned short)(u >> 16);
}

// ---------------------------------------------------------------------------
// K0: weight prep. in: fp32 [n][c][d]  ->  out: bf16 [n][d][c] (transposed)
// ---------------------------------------------------------------------------
__global__ __launch_bounds__(256)
void wprep_kernel(const float* __restrict__ w1, const float* __restrict__ w2,
                  unsigned short* __restrict__ w1t, unsigned short* __restrict__ w2t)
{
    __shared__ float tile[32][33];
    const int which = blockIdx.z >> 3;
    const int n     = blockIdx.z & 7;
    const float*          src = (which ? w2 : w1) + (size_t)n * CH * CH;
    unsigned short*       dst = (which ? w2t : w1t) + (size_t)n * CH * CH;
    const int c0 = blockIdx.y * 32;
    const int d0 = blockIdx.x * 32;
    const int tx = threadIdx.x;
    const int ty = threadIdx.y;
#pragma unroll
    for (int i = 0; i < 32; i += 8)
        tile[ty + i][tx] = src[(size_t)(c0 + ty + i) * CH + d0 + tx];
    __syncthreads();
#pragma unroll
    for (int i = 0; i < 32; i += 8)
        dst[(size_t)(d0 + ty + i) * CH + c0 + tx] = f2bf(tile[tx][ty + i]);
}

// ---------------------------------------------------------------------------
// Double-buffered streamed-B GEMM over one 512-wide chunk (K = 512).
// A (BM x 512 bf16) in XOR-swizzled LDS; B = w[d][c] bf16 streamed from L2.
// Depth-1 prefetch, fully unrolled (static register indices only).
// ---------------------------------------------------------------------------
__device__ __forceinline__ void gemm_chunk(
    const unsigned short* __restrict__ wb,
    const unsigned char* lds,
    int nwoff, int l15, int kg,
    f32x4 (&acc)[4][8])
{
    s16x8 b0[8], b1[8], a0[4], a1[4];
    auto loadB = [&](s16x8 (&d)[8], int kt) {
#pragma unroll
        for (int ni = 0; ni < 8; ++ni)
            d[ni] = *(const s16x8*)(wb + (size_t)(nwoff + ni * 16 + l15) * CH + kt * 32 + kg * 8);
    };
    auto loadA = [&](s16x8 (&d)[4], int kt) {
#pragma unroll
        for (int mi = 0; mi < 4; ++mi) {
            int r = mi * 16 + l15;
            int byte = ((r * CH + kt * 32 + kg * 8) * 2) ^ ((r & 7) << 4);
            d[mi] = *(const s16x8*)(lds + byte);
        }
    };
    auto mm = [&](s16x8 (&a)[4], s16x8 (&b)[8]) {
#pragma unroll
        for (int ni = 0; ni < 8; ++ni)
#pragma unroll
            for (int mi = 0; mi < 4; ++mi)
                acc[mi][ni] = __builtin_amdgcn_mfma_f32_16x16x32_bf16(a[mi], b[ni], acc[mi][ni], 0, 0, 0);
    };

    loadB(b0, 0);
    loadA(a0, 0);
#pragma unroll
    for (int k2 = 0; k2 < 8; ++k2) {
        loadB(b1, 2 * k2 + 1);
        loadA(a1, 2 * k2 + 1);
        mm(a0, b0);                 // prefetched b1/a1 in flight under these MFMAs
        if (k2 < 7) {
            loadB(b0, 2 * k2 + 2);
            loadA(a0, 2 * k2 + 2);
        }
        mm(a1, b1);
    }
}

// ---------------------------------------------------------------------------
// K1: fused chunk MLP.  grid = (TOKENS/BM, NCH) — bid.x (tile) fastest, so
// co-resident blocks share the same chunk n => weight panel stays in L2.
// block = 256 (4 waves), each wave owns a 128-wide N slice.
// MID_BF: store pre-LN mid as bf16 (ws) instead of fp32 (d_out).
// ---------------------------------------------------------------------------
template<bool MID_BF>
__global__ __launch_bounds__(256, 2)
void mlp_kernel(const float* __restrict__ x,
                const unsigned short* __restrict__ w1t,
                const unsigned short* __restrict__ w2t,
                const float* __restrict__ b1,
                const float* __restrict__ b2,
                void* __restrict__ midv)
{
    __shared__ unsigned char lds[BM * CH * 2];   // 64 KB, Xc then H1 (aliased)
    const int tile = blockIdx.x;
    const int n    = blockIdx.y;
    const int tid  = threadIdx.x;
    const int wid  = tid >> 6;
    const int lane = tid & 63;
    const int row0 = tile * BM;

    // ---- stage Xc (fp32 -> bf16, swizzled) ----
    {
        const float* xc = x + (size_t)row0 * DMODEL + n * CH;
#pragma unroll
        for (int it = 0; it < 32; ++it) {
            int f = it * 256 + tid;
            int r = f >> 7;
            int c = (f & 127) << 2;
            const float4 v = *(const float4*)(xc + (size_t)r * DMODEL + c);
            unsigned lo = (unsigned)f2bf(v.x) | ((unsigned)f2bf(v.y) << 16);
            unsigned hi = (unsigned)f2bf(v.z) | ((unsigned)f2bf(v.w) << 16);
            int byte = ((r * CH + c) * 2) ^ ((r & 7) << 4);
            *(uint2*)(lds + byte) = make_uint2(lo, hi);
        }
    }
    __syncthreads();

    const int nwoff = wid * 128;
    const int l15   = lane & 15;
    const int kg    = lane >> 4;

    float b1v[8], b2v[8];
#pragma unroll
    for (int ni = 0; ni < 8; ++ni) {
        int col = nwoff + ni * 16 + l15;
        b1v[ni] = b1[n * CH + col];
        b2v[ni] = b2[n * CH + col];
    }

    f32x4 acc[4][8];
#pragma unroll
    for (int mi = 0; mi < 4; ++mi)
#pragma unroll
        for (int ni = 0; ni < 8; ++ni)
            acc[mi][ni] = (f32x4){0.f, 0.f, 0.f, 0.f};

    // ---- GEMM1 ----
    gemm_chunk(w1t + (size_t)n * CH * CH, lds, nwoff, l15, kg, acc);

    __syncthreads();   // all waves done reading Xc

    // ---- bias1 + exact GELU -> H1 bf16 into (aliased) LDS ----
#pragma unroll
    for (int mi = 0; mi < 4; ++mi)
#pragma unroll
        for (int ni = 0; ni < 8; ++ni)
#pragma unroll
            for (int r = 0; r < 4; ++r) {
                float v = acc[mi][ni][r] + b1v[ni];
                v = 0.5f * v * (1.0f + erff(v * 0.70710678118654752f));
                int row  = mi * 16 + kg * 4 + r;
                int col  = nwoff + ni * 16 + l15;
                int byte = ((row * CH + col) * 2) ^ ((row & 7) << 4);
                *(unsigned short*)(lds + byte) = f2bf(v);
            }
    __syncthreads();

#pragma unroll
    for (int mi = 0; mi < 4; ++mi)
#pragma unroll
        for (int ni = 0; ni < 8; ++ni)
            acc[mi][ni] = (f32x4){0.f, 0.f, 0.f, 0.f};

    // ---- GEMM2 ----
    gemm_chunk(w2t + (size_t)n * CH * CH, lds, nwoff, l15, kg, acc);

    // ---- epilogue: + b2 + residual x, store pre-LN mid ----
    const float* xr = x + (size_t)row0 * DMODEL + n * CH;
#pragma unroll
    for (int mi = 0; mi < 4; ++mi)
#pragma unroll
        for (int ni = 0; ni < 8; ++ni)
#pragma unroll
            for (int r = 0; r < 4; ++r) {
                int row = mi * 16 + kg * 4 + r;
                int col = nwoff + ni * 16 + l15;
                float v = acc[mi][ni][r] + b2v[ni] + xr[(size_t)row * DMODEL + col];
                size_t idx = (size_t)(row0 + row) * DMODEL + n * CH + col;
                if constexpr (MID_BF)
                    ((unsigned short*)midv)[idx] = f2bf(v);
                else
                    ((float*)midv)[idx] = v;
            }
}

// ---------------------------------------------------------------------------
// K2: LayerNorm. One block per row; each thread owns 16 contiguous elements.
// MID_BF: mid is bf16 in ws; else fp32 (in-place on d_out).
// ---------------------------------------------------------------------------
template<bool MID_BF>
__global__ __launch_bounds__(256)
void ln_kernel(const void* __restrict__ midv, float* __restrict__ out,
               const float* __restrict__ g, const float* __restrict__ bt)
{
    __shared__ float red[8];
    const int row = blockIdx.x;
    const int tid = threadIdx.x;
    const int c0  = tid * 16;

    float v[16];
    if constexpr (MID_BF) {
        const unsigned short* p = (const unsigned short*)midv + (size_t)row * DMODEL + c0;
        uint4 q0 = *(const uint4*)(p);
        uint4 q1 = *(const uint4*)(p + 8);
        unsigned w[8] = {q0.x, q0.y, q0.z, q0.w, q1.x, q1.y, q1.z, q1.w};
#pragma unroll
        for (int i = 0; i < 8; ++i) {
            v[2 * i]     = __uint_as_float(w[i] << 16);
            v[2 * i + 1] = __uint_as_float(w[i] & 0xffff0000u);
        }
    } else {
        const float* p = (const float*)midv + (size_t)row * DMODEL + c0;
#pragma unroll
        for (int i = 0; i < 4; ++i) {
            float4 q = *(const float4*)(p + i * 4);
            v[4 * i] = q.x; v[4 * i + 1] = q.y; v[4 * i + 2] = q.z; v[4 * i + 3] = q.w;
        }
    }

    float s = 0.f, ss = 0.f;
#pragma unroll
    for (int i = 0; i < 16; ++i) { s += v[i]; ss += v[i] * v[i]; }
#pragma unroll
    for (int o = 32; o > 0; o >>= 1) {
        s  += __shfl_xor(s, o, 64);
        ss += __shfl_xor(ss, o, 64);
    }
    const int wid = tid >> 6, lane = tid & 63;
    if (lane == 0) { red[wid] = s; red[4 + wid] = ss; }
    __syncthreads();
    s  = red[0] + red[1] + red[2] + red[3];
    ss = red[4] + red[5] + red[6] + red[7];
    const float mu   = s * (1.f / DMODEL);
    const float var  = ss * (1.f / DMODEL) - mu * mu;
    const float rstd = rsqrtf(var + 1e-5f);

    float* po = out + (size_t)row * DMODEL + c0;
#pragma unroll
    for (int i = 0; i < 4; ++i) {
        float4 gv = *(const float4*)(g  + c0 + i * 4);
        float4 bv = *(const float4*)(bt + c0 + i * 4);
        float4 o;
        o.x = (v[4 * i]     - mu) * rstd * gv.x + bv.x;
        o.y = (v[4 * i + 1] - mu) * rstd * gv.y + bv.y;
        o.z = (v[4 * i + 2] - mu) * rstd * gv.z + bv.z;
        o.w = (v[4 * i + 3] - mu) * rstd * gv.w + bv.w;
        *(float4*)(po + i * 4) = o;
    }
}

// ---------------------------------------------------------------------------
extern "C" void kernel_launch(void* const* d_in, const int* in_sizes, int n_in,
                              void* d_out, int out_size, void* d_ws, size_t ws_size,
                              hipStream_t stream)
{
    const float* x    = (const float*)d_in[0];
    const float* w1   = (const float*)d_in[1];
    const float* b1   = (const float*)d_in[2];
    const float* w2   = (const float*)d_in[3];
    const float* b2   = (const float*)d_in[4];
    const float* ln_g = (const float*)d_in[5];
    const float* ln_b = (const float*)d_in[6];
    float* out = (float*)d_out;

    unsigned short* w1t = (unsigned short*)d_ws;           // 4 MiB
    unsigned short* w2t = w1t + (size_t)NCH * CH * CH;     // 4 MiB

    const size_t wbytes   = (size_t)2 * NCH * CH * CH * 2; // 8 MiB
    const size_t midbytes = (size_t)TOKENS * DMODEL * 2;   // 128 MiB (bf16)
    const bool bf_mid = ws_size >= wbytes + midbytes;

    wprep_kernel<<<dim3(16, 16, 16), dim3(32, 8), 0, stream>>>(w1, w2, w1t, w2t);

    if (bf_mid) {
        unsigned short* mid = (unsigned short*)((char*)d_ws + wbytes);
        mlp_kernel<true><<<dim3(TOKENS / BM, NCH), dim3(256), 0, stream>>>(x, w1t, w2t, b1, b2, mid);
        ln_kernel<true><<<dim3(TOKENS), dim3(256), 0, stream>>>(mid, out, ln_g, ln_b);
    } else {
        mlp_kernel<false><<<dim3(TOKENS / BM, NCH), dim3(256), 0, stream>>>(x, w1t, w2t, b1, b2, out);
        ln_kernel<false><<<dim3(TOKENS), dim3(256), 0, stream>>>(out, out, ln_g, ln_b);
    }
}

// Round 4
// 360.046 us; speedup vs baseline: 2.1948x; 2.1948x over previous
//
#include <hip/hip_runtime.h>
#include <hip/hip_bf16.h>

#define TOKENS 16384
#define DMODEL 4096
#define NCH 8
#define CH 512
#define BM 64

typedef short s16x8 __attribute__((ext_vector_type(8)));
typedef float f32x4 __attribute__((ext_vector_type(4)));

__device__ __forceinline__ unsigned short f2bf(float f) {
    unsigned u = __float_as_uint(f);
    u += 0x7fffu + ((u >> 16) & 1u);
    return (unsigned short)(u >> 16);
}

// ---------------------------------------------------------------------------
// K0: weight prep into MFMA-fragment-packed layout.
// w[n][c][d] fp32  ->  P[n][kt][nb][lane][8] bf16, where the 16B at
// (kt, nb, lane=kg*16+l15) is exactly the B-frag lane data:
//   W[k = kt*32 + kg*8 + j][ncol = nb*16 + l15], j=0..7 (k ascending).
// B-loads in the GEMM become 64-lane contiguous 1KB reads.
// ---------------------------------------------------------------------------
__global__ __launch_bounds__(256)
void wprep_kernel(const float* __restrict__ w1, const float* __restrict__ w2,
                  unsigned short* __restrict__ p1, unsigned short* __restrict__ p2)
{
    const int lane = threadIdx.x;        // 0..63
    const int sub  = threadIdx.y;        // 0..3
    const int kt   = blockIdx.x;         // 0..15
    const int nb   = blockIdx.y * 4 + sub; // 0..31
    const int which = blockIdx.z >> 3;
    const int n     = blockIdx.z & 7;

    const int kg  = lane >> 4;
    const int l15 = lane & 15;

    const float* src = (which ? w2 : w1) + (size_t)n * CH * CH;
    unsigned short* dst = (which ? p2 : p1) + (size_t)n * CH * CH
                        + ((size_t)(kt * 32 + nb) * 64 + lane) * 8;

    unsigned short v[8];
#pragma unroll
    for (int j = 0; j < 8; ++j)
        v[j] = f2bf(src[(size_t)(kt * 32 + kg * 8 + j) * CH + nb * 16 + l15]);

    uint4 q;
    q.x = (unsigned)v[0] | ((unsigned)v[1] << 16);
    q.y = (unsigned)v[2] | ((unsigned)v[3] << 16);
    q.z = (unsigned)v[4] | ((unsigned)v[5] << 16);
    q.w = (unsigned)v[6] | ((unsigned)v[7] << 16);
    *(uint4*)dst = q;
}

// ---------------------------------------------------------------------------
// Streamed-B GEMM over one 512-wide chunk (K = 512), packed-B layout.
// A (BM x 512 bf16) in XOR-swizzled LDS; B read as contiguous 1KB frag lines.
// Depth-1 ping-pong prefetch of B (static buffer names only).
// ---------------------------------------------------------------------------
__device__ __forceinline__ void gemm_chunk(
    const unsigned short* __restrict__ wp,   // packed chunk base
    const unsigned char* lds,
    int wid, int lane, int l15, int kg,
    f32x4 (&acc)[4][8])
{
    s16x8 b0[8], b1[8], a[4];
    auto loadB = [&](s16x8 (&d)[8], int kt) {
#pragma unroll
        for (int ni = 0; ni < 8; ++ni)
            d[ni] = *(const s16x8*)(wp + ((size_t)(kt * 32 + wid * 8 + ni) * 64 + lane) * 8);
    };
    auto loadA = [&](s16x8 (&d)[4], int kt) {
#pragma unroll
        for (int mi = 0; mi < 4; ++mi) {
            int r = mi * 16 + l15;
            int byte = ((r * CH + kt * 32 + kg * 8) * 2) ^ ((r & 7) << 4);
            d[mi] = *(const s16x8*)(lds + byte);
        }
    };
    auto mm = [&](s16x8 (&aa)[4], s16x8 (&b)[8]) {
#pragma unroll
        for (int ni = 0; ni < 8; ++ni)
#pragma unroll
            for (int mi = 0; mi < 4; ++mi)
                acc[mi][ni] = __builtin_amdgcn_mfma_f32_16x16x32_bf16(aa[mi], b[ni], acc[mi][ni], 0, 0, 0);
    };

    loadB(b0, 0);
#pragma unroll 1
    for (int k2 = 0; k2 < 8; ++k2) {
        loadB(b1, 2 * k2 + 1);          // in flight under mm(b0)
        loadA(a, 2 * k2);
        mm(a, b0);
        if (k2 < 7) loadB(b0, 2 * k2 + 2);  // in flight under mm(b1)
        loadA(a, 2 * k2 + 1);
        mm(a, b1);
    }
}

// ---------------------------------------------------------------------------
// K1: fused chunk MLP.  grid = (TOKENS/BM, NCH) — tile fastest so co-resident
// blocks share a chunk's weight panel in L2. block = 256 (4 waves), each wave
// owns a 128-wide N slice. Writes pre-LN fp32 (full-line stores) into d_out.
// ---------------------------------------------------------------------------
__global__ __launch_bounds__(256, 2)
void mlp_kernel(const float* __restrict__ x,
                const unsigned short* __restrict__ p1,
                const unsigned short* __restrict__ p2,
                const float* __restrict__ b1,
                const float* __restrict__ b2,
                float* __restrict__ mid)
{
    __shared__ unsigned char lds[BM * CH * 2];   // 64 KB, Xc then H1 (aliased)
    const int tile = blockIdx.x;
    const int n    = blockIdx.y;
    const int tid  = threadIdx.x;
    const int wid  = tid >> 6;
    const int lane = tid & 63;
    const int row0 = tile * BM;

    // ---- stage Xc (fp32 -> bf16, swizzled) ----
    {
        const float* xc = x + (size_t)row0 * DMODEL + n * CH;
#pragma unroll
        for (int it = 0; it < 32; ++it) {
            int f = it * 256 + tid;
            int r = f >> 7;
            int c = (f & 127) << 2;
            const float4 v = *(const float4*)(xc + (size_t)r * DMODEL + c);
            unsigned lo = (unsigned)f2bf(v.x) | ((unsigned)f2bf(v.y) << 16);
            unsigned hi = (unsigned)f2bf(v.z) | ((unsigned)f2bf(v.w) << 16);
            int byte = ((r * CH + c) * 2) ^ ((r & 7) << 4);
            *(uint2*)(lds + byte) = make_uint2(lo, hi);
        }
    }
    __syncthreads();

    const int nwoff = wid * 128;
    const int l15   = lane & 15;
    const int kg    = lane >> 4;

    float b1v[8], b2v[8];
#pragma unroll
    for (int ni = 0; ni < 8; ++ni) {
        int col = nwoff + ni * 16 + l15;
        b1v[ni] = b1[n * CH + col];
        b2v[ni] = b2[n * CH + col];
    }

    f32x4 acc[4][8];
#pragma unroll
    for (int mi = 0; mi < 4; ++mi)
#pragma unroll
        for (int ni = 0; ni < 8; ++ni)
            acc[mi][ni] = (f32x4){0.f, 0.f, 0.f, 0.f};

    // ---- GEMM1 ----
    gemm_chunk(p1 + (size_t)n * CH * CH, lds, wid, lane, l15, kg, acc);

    __syncthreads();   // all waves done reading Xc

    // ---- bias1 + exact GELU -> H1 bf16 into (aliased) LDS ----
#pragma unroll
    for (int mi = 0; mi < 4; ++mi)
#pragma unroll
        for (int ni = 0; ni < 8; ++ni)
#pragma unroll
            for (int r = 0; r < 4; ++r) {
                float v = acc[mi][ni][r] + b1v[ni];
                v = 0.5f * v * (1.0f + erff(v * 0.70710678118654752f));
                int row  = mi * 16 + kg * 4 + r;
                int col  = nwoff + ni * 16 + l15;
                int byte = ((row * CH + col) * 2) ^ ((row & 7) << 4);
                *(unsigned short*)(lds + byte) = f2bf(v);
            }
    __syncthreads();

#pragma unroll
    for (int mi = 0; mi < 4; ++mi)
#pragma unroll
        for (int ni = 0; ni < 8; ++ni)
            acc[mi][ni] = (f32x4){0.f, 0.f, 0.f, 0.f};

    // ---- GEMM2 ----
    gemm_chunk(p2 + (size_t)n * CH * CH, lds, wid, lane, l15, kg, acc);

    // ---- epilogue: + b2 + residual x, store fp32 pre-LN (full 64B lines) ----
    const float* xr = x   + (size_t)row0 * DMODEL + n * CH;
    float*       mr = mid + (size_t)row0 * DMODEL + n * CH;
#pragma unroll
    for (int mi = 0; mi < 4; ++mi)
#pragma unroll
        for (int ni = 0; ni < 8; ++ni)
#pragma unroll
            for (int r = 0; r < 4; ++r) {
                int row = mi * 16 + kg * 4 + r;
                int col = nwoff + ni * 16 + l15;
                float v = acc[mi][ni][r] + b2v[ni] + xr[(size_t)row * DMODEL + col];
                mr[(size_t)row * DMODEL + col] = v;
            }
}

// ---------------------------------------------------------------------------
// K2: in-place LayerNorm over rows of `out` (pre-LN values written by K1).
// ---------------------------------------------------------------------------
__global__ __launch_bounds__(256)
void ln_kernel(float* __restrict__ out,
               const float* __restrict__ g,
               const float* __restrict__ bt)
{
    __shared__ float red[8];
    const int row = blockIdx.x;
    const int tid = threadIdx.x;
    float* p = out + (size_t)row * DMODEL;

    float4 v[4];
    float s = 0.f, ss = 0.f;
#pragma unroll
    for (int i = 0; i < 4; ++i) {
        v[i] = *(const float4*)(p + (i * 256 + tid) * 4);
        s  += v[i].x + v[i].y + v[i].z + v[i].w;
        ss += v[i].x * v[i].x + v[i].y * v[i].y + v[i].z * v[i].z + v[i].w * v[i].w;
    }
#pragma unroll
    for (int o = 32; o > 0; o >>= 1) {
        s  += __shfl_xor(s, o, 64);
        ss += __shfl_xor(ss, o, 64);
    }
    const int wid = tid >> 6, lane = tid & 63;
    if (lane == 0) { red[wid] = s; red[4 + wid] = ss; }
    __syncthreads();
    s  = red[0] + red[1] + red[2] + red[3];
    ss = red[4] + red[5] + red[6] + red[7];
    const float mu   = s * (1.f / DMODEL);
    const float var  = ss * (1.f / DMODEL) - mu * mu;
    const float rstd = rsqrtf(var + 1e-5f);

#pragma unroll
    for (int i = 0; i < 4; ++i) {
        int c = (i * 256 + tid) * 4;
        float4 gv = *(const float4*)(g + c);
        float4 bv = *(const float4*)(bt + c);
        float4 o;
        o.x = (v[i].x - mu) * rstd * gv.x + bv.x;
        o.y = (v[i].y - mu) * rstd * gv.y + bv.y;
        o.z = (v[i].z - mu) * rstd * gv.z + bv.z;
        o.w = (v[i].w - mu) * rstd * gv.w + bv.w;
        *(float4*)(p + c) = o;
    }
}

// ---------------------------------------------------------------------------
extern "C" void kernel_launch(void* const* d_in, const int* in_sizes, int n_in,
                              void* d_out, int out_size, void* d_ws, size_t ws_size,
                              hipStream_t stream)
{
    const float* x    = (const float*)d_in[0];
    const float* w1   = (const float*)d_in[1];
    const float* b1   = (const float*)d_in[2];
    const float* w2   = (const float*)d_in[3];
    const float* b2   = (const float*)d_in[4];
    const float* ln_g = (const float*)d_in[5];
    const float* ln_b = (const float*)d_in[6];
    float* out = (float*)d_out;

    unsigned short* p1 = (unsigned short*)d_ws;           // 4 MiB packed W1
    unsigned short* p2 = p1 + (size_t)NCH * CH * CH;      // 4 MiB packed W2

    wprep_kernel<<<dim3(16, 8, 16), dim3(64, 4), 0, stream>>>(w1, w2, p1, p2);
    mlp_kernel<<<dim3(TOKENS / BM, NCH), dim3(256), 0, stream>>>(x, p1, p2, b1, b2, out);
    ln_kernel<<<dim3(TOKENS), dim3(256), 0, stream>>>(out, ln_g, ln_b);
}

// Round 5
// 339.832 us; speedup vs baseline: 2.3254x; 1.0595x over previous
//
#include <hip/hip_runtime.h>
#include <hip/hip_bf16.h>

#define TOKENS 16384
#define DMODEL 4096
#define NCH 8
#define CH 512
#define BM 64

typedef short s16x8 __attribute__((ext_vector_type(8)));
typedef float f32x4 __attribute__((ext_vector_type(4)));

__device__ __forceinline__ unsigned short f2bf(float f) {
    unsigned u = __float_as_uint(f);
    u += 0x7fffu + ((u >> 16) & 1u);
    return (unsigned short)(u >> 16);
}

// tanh-form GELU via single v_exp: gelu(x) = x * e/(e+1), e = exp(2*sqrt(2/pi)*(x+0.044715x^3))
__device__ __forceinline__ float gelu_fast(float x) {
    float u = 1.5957691216057308f * x * (1.0f + 0.044715f * x * x);
    float e = __expf(u);
    return x - x * __builtin_amdgcn_rcpf(e + 1.0f);
}

// ---------------------------------------------------------------------------
// K0: weight prep into MFMA-fragment-packed layout.
// w[n][c][d] fp32 -> P[n][kt][nb][lane][8] bf16; the 16B at (kt,nb,lane=kg*16+l15)
// holds W[kt*32+kg*8+j][nb*16+l15], j=0..7. B-frag loads become 64-lane
// contiguous 1KB reads.
// ---------------------------------------------------------------------------
__global__ __launch_bounds__(256)
void wprep_kernel(const float* __restrict__ w1, const float* __restrict__ w2,
                  unsigned short* __restrict__ p1, unsigned short* __restrict__ p2)
{
    const int lane = threadIdx.x;          // 0..63
    const int sub  = threadIdx.y;          // 0..3
    const int kt   = blockIdx.x;           // 0..15
    const int nb   = blockIdx.y * 4 + sub; // 0..31
    const int which = blockIdx.z >> 3;
    const int n     = blockIdx.z & 7;

    const int kg  = lane >> 4;
    const int l15 = lane & 15;

    const float* src = (which ? w2 : w1) + (size_t)n * CH * CH;
    unsigned short* dst = (which ? p2 : p1) + (size_t)n * CH * CH
                        + ((size_t)(kt * 32 + nb) * 64 + lane) * 8;

    unsigned short v[8];
#pragma unroll
    for (int j = 0; j < 8; ++j)
        v[j] = f2bf(src[(size_t)(kt * 32 + kg * 8 + j) * CH + nb * 16 + l15]);

    uint4 q;
    q.x = (unsigned)v[0] | ((unsigned)v[1] << 16);
    q.y = (unsigned)v[2] | ((unsigned)v[3] << 16);
    q.z = (unsigned)v[4] | ((unsigned)v[5] << 16);
    q.w = (unsigned)v[6] | ((unsigned)v[7] << 16);
    *(uint4*)dst = q;
}

// ---------------------------------------------------------------------------
// One N-half GEMM pass over K=512 (16 kt-steps), acc 4x4 (64 regs).
// DEPTH=3: rotating 3-buffer B pipeline (issue->consume distance = 2 kt).
// DEPTH=2: ping-pong (used while the GELU stash occupies 32 regs).
// ---------------------------------------------------------------------------
template<int DEPTH>
__device__ __forceinline__ void gemm_half(
    const unsigned short* __restrict__ wp,   // packed panel base (chunk n)
    const unsigned char* lds,
    int nbase,                               // wid*8 + half*4
    int lane, int l15, int kg,
    f32x4 (&acc)[4][4])
{
    s16x8 b0[4], b1[4], b2[4], a[4];
    auto loadB = [&](s16x8 (&d)[4], int kt) {
        const unsigned short* p = wp + ((size_t)(kt * 32 + nbase) * 64 + lane) * 8;
#pragma unroll
        for (int ni = 0; ni < 4; ++ni)
            d[ni] = *(const s16x8*)(p + (size_t)ni * 64 * 8);
    };
    auto loadA = [&](int kt) {
#pragma unroll
        for (int mi = 0; mi < 4; ++mi) {
            int r = mi * 16 + l15;
            int byte = ((r * CH + kt * 32 + kg * 8) * 2) ^ ((r & 7) << 4);
            a[mi] = *(const s16x8*)(lds + byte);
        }
    };
    auto mm = [&](s16x8 (&b)[4]) {
#pragma unroll
        for (int ni = 0; ni < 4; ++ni)
#pragma unroll
            for (int mi = 0; mi < 4; ++mi)
                acc[mi][ni] = __builtin_amdgcn_mfma_f32_16x16x32_bf16(a[mi], b[ni], acc[mi][ni], 0, 0, 0);
    };

    if constexpr (DEPTH == 3) {
        loadB(b0, 0); loadB(b1, 1); loadB(b2, 2);
#pragma unroll 1
        for (int k3 = 0; k3 < 4; ++k3) {
            const int k = k3 * 3;                 // steps 0..11
            loadA(k);     mm(b0); loadB(b0, k + 3);
            loadA(k + 1); mm(b1); loadB(b1, k + 4);
            loadA(k + 2); mm(b2); loadB(b2, k + 5);
        }
        loadA(12); mm(b0); loadB(b0, 15);
        loadA(13); mm(b1);
        loadA(14); mm(b2);
        loadA(15); mm(b0);
    } else {
        loadB(b0, 0); loadB(b1, 1);
#pragma unroll 1
        for (int k2 = 0; k2 < 7; ++k2) {
            const int k = k2 * 2;                 // steps 0..13
            loadA(k);     mm(b0); loadB(b0, k + 2);
            loadA(k + 1); mm(b1); loadB(b1, k + 3);
        }
        loadA(14); mm(b0);
        loadA(15); mm(b1);
    }
}

// ---------------------------------------------------------------------------
// K1: fused chunk MLP.  grid = (TOKENS/BM, NCH) — tile fastest so co-resident
// blocks share a chunk's weight panel (L1/L2 dedup). block = 256 (4 waves),
// wave owns a 128-wide N slice computed as two 64-wide passes (acc 4x4).
// ---------------------------------------------------------------------------
__global__ __launch_bounds__(256, 2)
void mlp_kernel(const float* __restrict__ x,
                const unsigned short* __restrict__ p1,
                const unsigned short* __restrict__ p2,
                const float* __restrict__ b1,
                const float* __restrict__ b2,
                float* __restrict__ mid)
{
    __shared__ unsigned char lds[BM * CH * 2];   // 64 KB, Xc then H1 (aliased)
    const int tile = blockIdx.x;
    const int n    = blockIdx.y;
    const int tid  = threadIdx.x;
    const int wid  = tid >> 6;
    const int lane = tid & 63;
    const int row0 = tile * BM;

    // ---- stage Xc (fp32 -> bf16, swizzled) ----
    {
        const float* xc = x + (size_t)row0 * DMODEL + n * CH;
#pragma unroll
        for (int it = 0; it < 32; ++it) {
            int f = it * 256 + tid;
            int r = f >> 7;
            int c = (f & 127) << 2;
            const float4 v = *(const float4*)(xc + (size_t)r * DMODEL + c);
            unsigned lo = (unsigned)f2bf(v.x) | ((unsigned)f2bf(v.y) << 16);
            unsigned hi = (unsigned)f2bf(v.z) | ((unsigned)f2bf(v.w) << 16);
            int byte = ((r * CH + c) * 2) ^ ((r & 7) << 4);
            *(uint2*)(lds + byte) = make_uint2(lo, hi);
        }
    }
    __syncthreads();

    const int nwoff = wid * 128;
    const int l15   = lane & 15;
    const int kg    = lane >> 4;

    float b1v[8], b2v[8];   // [half*4 + ni]
#pragma unroll
    for (int h = 0; h < 2; ++h)
#pragma unroll
        for (int ni = 0; ni < 4; ++ni) {
            int col = n * CH + nwoff + h * 64 + ni * 16 + l15;
            b1v[h * 4 + ni] = b1[col];
            b2v[h * 4 + ni] = b2[col];
        }

    const unsigned short* p1n = p1 + (size_t)n * CH * CH;
    const unsigned short* p2n = p2 + (size_t)n * CH * CH;

    f32x4 acc[4][4];
    auto zacc = [&]() {
#pragma unroll
        for (int mi = 0; mi < 4; ++mi)
#pragma unroll
            for (int ni = 0; ni < 4; ++ni)
                acc[mi][ni] = (f32x4){0.f, 0.f, 0.f, 0.f};
    };

    // ================= GEMM1 =================
    zacc();
    gemm_half<3>(p1n, lds, wid * 8 + 0, lane, l15, kg, acc);

    // pass0: bias + GELU -> packed bf16 register stash (32 u32)
    unsigned g0[4][4][2];
#pragma unroll
    for (int mi = 0; mi < 4; ++mi)
#pragma unroll
        for (int ni = 0; ni < 4; ++ni)
#pragma unroll
            for (int j = 0; j < 2; ++j) {
                float v0 = gelu_fast(acc[mi][ni][2 * j]     + b1v[ni]);
                float v1 = gelu_fast(acc[mi][ni][2 * j + 1] + b1v[ni]);
                g0[mi][ni][j] = (unsigned)f2bf(v0) | ((unsigned)f2bf(v1) << 16);
            }

    zacc();
    gemm_half<2>(p1n, lds, wid * 8 + 4, lane, l15, kg, acc);

    __syncthreads();   // all waves done reading Xc

    // write H1 (bf16, swizzled) — pass0 from stash, pass1 from acc
#pragma unroll
    for (int mi = 0; mi < 4; ++mi)
#pragma unroll
        for (int ni = 0; ni < 4; ++ni)
#pragma unroll
            for (int j = 0; j < 2; ++j) {
                int col  = nwoff + ni * 16 + l15;
                int row  = mi * 16 + kg * 4 + 2 * j;
                int byte0 = ((row * CH + col) * 2) ^ ((row & 7) << 4);
                *(unsigned short*)(lds + byte0) = (unsigned short)(g0[mi][ni][j] & 0xffff);
                int row1 = row + 1;
                int byte1 = ((row1 * CH + col) * 2) ^ ((row1 & 7) << 4);
                *(unsigned short*)(lds + byte1) = (unsigned short)(g0[mi][ni][j] >> 16);
            }
#pragma unroll
    for (int mi = 0; mi < 4; ++mi)
#pragma unroll
        for (int ni = 0; ni < 4; ++ni)
#pragma unroll
            for (int r = 0; r < 4; ++r) {
                float v = gelu_fast(acc[mi][ni][r] + b1v[4 + ni]);
                int col  = nwoff + 64 + ni * 16 + l15;
                int row  = mi * 16 + kg * 4 + r;
                int byte = ((row * CH + col) * 2) ^ ((row & 7) << 4);
                *(unsigned short*)(lds + byte) = f2bf(v);
            }
    __syncthreads();

    // ================= GEMM2 =================
    const float* xr = x   + (size_t)row0 * DMODEL + n * CH;
    float*       mr = mid + (size_t)row0 * DMODEL + n * CH;

#pragma unroll
    for (int h = 0; h < 2; ++h) {
        zacc();
        if (h == 0) gemm_half<3>(p2n, lds, wid * 8 + 0, lane, l15, kg, acc);
        else        gemm_half<3>(p2n, lds, wid * 8 + 4, lane, l15, kg, acc);
#pragma unroll
        for (int mi = 0; mi < 4; ++mi)
#pragma unroll
            for (int ni = 0; ni < 4; ++ni)
#pragma unroll
                for (int r = 0; r < 4; ++r) {
                    int row = mi * 16 + kg * 4 + r;
                    int col = nwoff + h * 64 + ni * 16 + l15;
                    float v = acc[mi][ni][r] + b2v[h * 4 + ni] + xr[(size_t)row * DMODEL + col];
                    mr[(size_t)row * DMODEL + col] = v;
                }
    }
}

// ---------------------------------------------------------------------------
// K2: in-place LayerNorm over rows of `out`.
// ---------------------------------------------------------------------------
__global__ __launch_bounds__(256)
void ln_kernel(float* __restrict__ out,
               const float* __restrict__ g,
               const float* __restrict__ bt)
{
    __shared__ float red[8];
    const int row = blockIdx.x;
    const int tid = threadIdx.x;
    float* p = out + (size_t)row * DMODEL;

    float4 v[4];
    float s = 0.f, ss = 0.f;
#pragma unroll
    for (int i = 0; i < 4; ++i) {
        v[i] = *(const float4*)(p + (i * 256 + tid) * 4);
        s  += v[i].x + v[i].y + v[i].z + v[i].w;
        ss += v[i].x * v[i].x + v[i].y * v[i].y + v[i].z * v[i].z + v[i].w * v[i].w;
    }
#pragma unroll
    for (int o = 32; o > 0; o >>= 1) {
        s  += __shfl_xor(s, o, 64);
        ss += __shfl_xor(ss, o, 64);
    }
    const int wid = tid >> 6, lane = tid & 63;
    if (lane == 0) { red[wid] = s; red[4 + wid] = ss; }
    __syncthreads();
    s  = red[0] + red[1] + red[2] + red[3];
    ss = red[4] + red[5] + red[6] + red[7];
    const float mu   = s * (1.f / DMODEL);
    const float var  = ss * (1.f / DMODEL) - mu * mu;
    const float rstd = rsqrtf(var + 1e-5f);

#pragma unroll
    for (int i = 0; i < 4; ++i) {
        int c = (i * 256 + tid) * 4;
        float4 gv = *(const float4*)(g + c);
        float4 bv = *(const float4*)(bt + c);
        float4 o;
        o.x = (v[i].x - mu) * rstd * gv.x + bv.x;
        o.y = (v[i].y - mu) * rstd * gv.y + bv.y;
        o.z = (v[i].z - mu) * rstd * gv.z + bv.z;
        o.w = (v[i].w - mu) * rstd * gv.w + bv.w;
        *(float4*)(p + c) = o;
    }
}

// ---------------------------------------------------------------------------
extern "C" void kernel_launch(void* const* d_in, const int* in_sizes, int n_in,
                              void* d_out, int out_size, void* d_ws, size_t ws_size,
                              hipStream_t stream)
{
    const float* x    = (const float*)d_in[0];
    const float* w1   = (const float*)d_in[1];
    const float* b1   = (const float*)d_in[2];
    const float* w2   = (const float*)d_in[3];
    const float* b2   = (const float*)d_in[4];
    const float* ln_g = (const float*)d_in[5];
    const float* ln_b = (const float*)d_in[6];
    float* out = (float*)d_out;

    unsigned short* p1 = (unsigned short*)d_ws;           // 4 MiB packed W1
    unsigned short* p2 = p1 + (size_t)NCH * CH * CH;      // 4 MiB packed W2

    wprep_kernel<<<dim3(16, 8, 16), dim3(64, 4), 0, stream>>>(w1, w2, p1, p2);
    mlp_kernel<<<dim3(TOKENS / BM, NCH), dim3(256), 0, stream>>>(x, p1, p2, b1, b2, out);
    ln_kernel<<<dim3(TOKENS), dim3(256), 0, stream>>>(out, ln_g, ln_b);
}